// Round 1
// baseline (230.933 us; speedup 1.0000x reference)
//
#include <hip/hip_runtime.h>
#include <hip/hip_bf16.h>

typedef __attribute__((ext_vector_type(8))) __bf16 bf16x8;
typedef __attribute__((ext_vector_type(4))) float f32x4;
typedef __attribute__((ext_vector_type(4))) int int4v;

#define NB 8
#define NN 2048
#define ND 256

// ---------------------------------------------------------------------------
// K0: wl[d] = sum_o a[o]*W[o][d], wr[d] = sum_o a[256+o]*W[o][d]
// (el = h@a_left = x@wl exactly in f32 -> scores near-exact)
// ---------------------------------------------------------------------------
__global__ __launch_bounds__(256) void k0_wvec(
    const float* __restrict__ W, const float* __restrict__ a,
    float* __restrict__ wl, float* __restrict__ wr) {
  int w = threadIdx.x >> 6, l = threadIdx.x & 63;
  f32x4 sl = {0.f, 0.f, 0.f, 0.f}, sr = {0.f, 0.f, 0.f, 0.f};
  for (int oo = 0; oo < 64; ++oo) {
    int o = w * 64 + oo;
    f32x4 wv = *(const f32x4*)(W + o * ND + l * 4);
    float al = a[o], ar = a[ND + o];
    sl += al * wv;
    sr += ar * wv;
  }
  __shared__ f32x4 bl[4][64], br[4][64];
  bl[w][l] = sl;
  br[w][l] = sr;
  __syncthreads();
  if (w == 0) {
    f32x4 tl = bl[0][l] + bl[1][l] + bl[2][l] + bl[3][l];
    f32x4 tr = br[0][l] + br[1][l] + br[2][l] + br[3][l];
    *(f32x4*)(wl + l * 4) = tl;
    *(f32x4*)(wr + l * 4) = tr;
  }
}

// ---------------------------------------------------------------------------
// K2: el[bn] = x[bn,:]*wl (f32), er[bn] = x[bn,:]*wr. 64 rows/block, 4 thr/row.
// ---------------------------------------------------------------------------
__global__ __launch_bounds__(256) void k2_elr(
    const float* __restrict__ x, const float* __restrict__ wl,
    const float* __restrict__ wr, float* __restrict__ el,
    float* __restrict__ er) {
  int t = threadIdx.x;
  int r = t >> 2, q = t & 3;
  long row = (long)blockIdx.x * 64 + r;
  const f32x4* xr = (const f32x4*)(x + row * ND);
  const f32x4* wl4 = (const f32x4*)wl;
  const f32x4* wr4 = (const f32x4*)wr;
  float sl = 0.f, sr = 0.f;
#pragma unroll
  for (int ii = 0; ii < 16; ++ii) {
    int idx = q + (ii << 2);
    f32x4 xv = xr[idx];
    f32x4 lv = wl4[idx];
    f32x4 rv = wr4[idx];
    sl += xv[0] * lv[0] + xv[1] * lv[1] + xv[2] * lv[2] + xv[3] * lv[3];
    sr += xv[0] * rv[0] + xv[1] * rv[1] + xv[2] * rv[2] + xv[3] * rv[3];
  }
  sl += __shfl_xor(sl, 1);
  sl += __shfl_xor(sl, 2);
  sr += __shfl_xor(sr, 1);
  sr += __shfl_xor(sr, 2);
  if (q == 0) {
    el[row] = sl;
    er[row] = sr;
  }
}

// ---------------------------------------------------------------------------
// K1: h = x @ W^T via bf16 MFMA 16x16x32; write hT[b][d][n] bf16 (transposed
// through LDS, stride padded to 34 to kill bank conflicts on the read-out).
// Block: 256 thr = 4 waves; tile 32 rows x 256 cols. wave: msub=w&1, nh=w>>1.
// A-frag: lane holds x[row=l&15][k=(l>>4)*8+e]; B-frag: W[o=l&15-col][k contig].
// ---------------------------------------------------------------------------
__global__ __launch_bounds__(256) void k1_h(
    const float* __restrict__ x, const float* __restrict__ W,
    __bf16* __restrict__ hT) {
  __shared__ __bf16 hlds[256 * 34];
  int tid = threadIdx.x;
  int wid = tid >> 6, lane = tid & 63;
  int msub = wid & 1, nh = wid >> 1;
  int lrow = lane & 15, kg = lane >> 4;
  int m0 = blockIdx.x * 32;
  int row = m0 + msub * 16 + lrow;

  f32x4 acc[8];
#pragma unroll
  for (int f = 0; f < 8; ++f) acc[f] = (f32x4){0.f, 0.f, 0.f, 0.f};

#pragma unroll
  for (int k0 = 0; k0 < ND; k0 += 32) {
    int kk = k0 + kg * 8;
    const f32x4* xa = (const f32x4*)(x + (long)row * ND + kk);
    f32x4 a0 = xa[0], a1 = xa[1];
    bf16x8 afrag;
    afrag[0] = (__bf16)a0[0]; afrag[1] = (__bf16)a0[1];
    afrag[2] = (__bf16)a0[2]; afrag[3] = (__bf16)a0[3];
    afrag[4] = (__bf16)a1[0]; afrag[5] = (__bf16)a1[1];
    afrag[6] = (__bf16)a1[2]; afrag[7] = (__bf16)a1[3];
#pragma unroll
    for (int f = 0; f < 8; ++f) {
      int o = nh * 128 + f * 16 + lrow;
      const f32x4* wb = (const f32x4*)(W + (long)o * ND + kk);
      f32x4 b0 = wb[0], b1 = wb[1];
      bf16x8 bfrag;
      bfrag[0] = (__bf16)b0[0]; bfrag[1] = (__bf16)b0[1];
      bfrag[2] = (__bf16)b0[2]; bfrag[3] = (__bf16)b0[3];
      bfrag[4] = (__bf16)b1[0]; bfrag[5] = (__bf16)b1[1];
      bfrag[6] = (__bf16)b1[2]; bfrag[7] = (__bf16)b1[3];
      acc[f] = __builtin_amdgcn_mfma_f32_16x16x32_bf16(afrag, bfrag, acc[f], 0, 0, 0);
    }
  }

  // C layout: row=(lane>>4)*4+r, col=lane&15. Write transposed into LDS.
#pragma unroll
  for (int f = 0; f < 8; ++f) {
    int d = nh * 128 + f * 16 + lrow;
#pragma unroll
    for (int r = 0; r < 4; ++r) {
      int nloc = msub * 16 + kg * 4 + r;
      hlds[d * 34 + nloc] = (__bf16)acc[f][r];
    }
  }
  __syncthreads();
  {
    int b = m0 >> 11;
    int n0 = m0 & (NN - 1);
    const int* src = (const int*)(hlds + tid * 34);  // 68B offset: 4-aligned
    int tmp[16];
#pragma unroll
    for (int j = 0; j < 16; ++j) tmp[j] = src[j];
    __bf16* dst = hT + ((long)b * ND + tid) * NN + n0;  // 64B-aligned
#pragma unroll
    for (int j = 0; j < 4; ++j)
      *(int4v*)(dst + j * 8) = *(int4v*)(tmp + j * 4);
  }
}

// ---------------------------------------------------------------------------
// K3: fused mask + softmax + PV.  out[b,i,:] = (sum_j p_ij h_j) / (sum_j p_ij)
// p_ij = adj ? exp(lrelu(el_i+er_j) - (el_i+16)) : 0   (el_i+16 >= all scores)
// Grid 512 = B*64 i-tiles of 32 rows; 4 waves: isub=w&1 (16 rows), dh=w>>1
// (128 cols = 8 frags). j-step 32 = one MFMA K. 1-deep adj/er prefetch.
// ---------------------------------------------------------------------------
__global__ __launch_bounds__(256) void k3_main(
    const int* __restrict__ adj, const __bf16* __restrict__ hT,
    const float* __restrict__ el, const float* __restrict__ er,
    float* __restrict__ out) {
  int blk = blockIdx.x;
  int b = blk >> 6;
  int it = blk & 63;
  int wid = threadIdx.x >> 6, lane = threadIdx.x & 63;
  int isub = wid & 1, dh = wid >> 1;
  int lrow = lane & 15, kg = lane >> 4;
  int irow = it * 32 + isub * 16 + lrow;  // 0..2047 within batch

  float eli = el[b * NN + irow];
  float el16 = eli + 16.0f;
  const int* adjrow = adj + ((long)b * NN + irow) * NN;
  const float* erb = er + b * NN;
  const __bf16* hTb = hT + (long)b * ND * NN;
  int d_base = dh * 128 + lrow;

  f32x4 acc[8];
#pragma unroll
  for (int f = 0; f < 8; ++f) acc[f] = (f32x4){0.f, 0.f, 0.f, 0.f};
  float den = 0.f;

  int jb0 = kg * 8;  // this lane-group's 8-j slice within the 32-j step
  int4v adjA = *(const int4v*)(adjrow + jb0);
  int4v adjB = *(const int4v*)(adjrow + jb0 + 4);
  f32x4 erA = *(const f32x4*)(erb + jb0);
  f32x4 erB = *(const f32x4*)(erb + jb0 + 4);

  for (int jb = 0; jb < NN; jb += 32) {
    int4v cadjA = adjA, cadjB = adjB;
    f32x4 cerA = erA, cerB = erB;
    int jn = jb + 32;
    if (jn < NN) {  // prefetch next iteration's adj/er
      adjA = *(const int4v*)(adjrow + jn + jb0);
      adjB = *(const int4v*)(adjrow + jn + jb0 + 4);
      erA = *(const f32x4*)(erb + jn + jb0);
      erB = *(const f32x4*)(erb + jn + jb0 + 4);
    }
    // p fragment (A-operand layout: row=l&15, k=(l>>4)*8+e contiguous)
    bf16x8 pfrag;
    float ps = 0.f;
#pragma unroll
    for (int e = 0; e < 8; ++e) {
      int aj = (e < 4) ? cadjA[e] : cadjB[e - 4];
      float erv = (e < 4) ? cerA[e] : cerB[e - 4];
      float z = eli + erv;
      float s = fmaxf(z, 0.2f * z);  // leaky relu
      float p = __expf(s - el16);
      p = (aj != 0) ? p : 0.0f;
      ps += p;
      pfrag[e] = (__bf16)p;
    }
    den += ps;
    // B frags from hT (contiguous 8 bf16 along j) + MFMA
    const __bf16* hcol = hTb + jb + jb0;
#pragma unroll
    for (int f = 0; f < 8; ++f) {
      int d = d_base + f * 16;
      bf16x8 bfrag = *(const bf16x8*)(hcol + (long)d * NN);
      acc[f] = __builtin_amdgcn_mfma_f32_16x16x32_bf16(pfrag, bfrag, acc[f], 0, 0, 0);
    }
  }

  // den: sum across the 4 k-groups (lanes with same l&15)
  den += __shfl_xor(den, 16);
  den += __shfl_xor(den, 32);
  // C rows are (kg*4+r); fetch that row's den from lane (kg*4+r)
  float rdiv[4];
#pragma unroll
  for (int r = 0; r < 4; ++r) rdiv[r] = 1.0f / __shfl(den, kg * 4 + r);

  float* outb = out + ((long)b * NN + it * 32 + isub * 16) * ND;
#pragma unroll
  for (int f = 0; f < 8; ++f) {
    int dcol = d_base + f * 16;
#pragma unroll
    for (int r = 0; r < 4; ++r) {
      int rrow = kg * 4 + r;
      outb[(long)rrow * ND + dcol] = acc[f][r] * rdiv[r];
    }
  }
}

// ---------------------------------------------------------------------------
extern "C" void kernel_launch(void* const* d_in, const int* in_sizes, int n_in,
                              void* d_out, int out_size, void* d_ws,
                              size_t ws_size, hipStream_t stream) {
  const float* x = (const float*)d_in[0];
  const int* adj = (const int*)d_in[1];
  const float* W = (const float*)d_in[2];
  const float* a = (const float*)d_in[3];
  float* out = (float*)d_out;

  char* ws = (char*)d_ws;
  __bf16* hT = (__bf16*)ws;                              // 8 MB
  float* el = (float*)(ws + 8u * 1024u * 1024u);         // 64 KB
  float* er = (float*)(ws + 8u * 1024u * 1024u + 65536u);
  float* wl = (float*)(ws + 8u * 1024u * 1024u + 131072u);  // 1 KB
  float* wr = (float*)(ws + 8u * 1024u * 1024u + 132096u);  // 1 KB

  k0_wvec<<<dim3(1), dim3(256), 0, stream>>>(W, a, wl, wr);
  k2_elr<<<dim3(256), dim3(256), 0, stream>>>(x, wl, wr, el, er);
  k1_h<<<dim3(512), dim3(256), 0, stream>>>(x, W, hT);
  k3_main<<<dim3(512), dim3(256), 0, stream>>>(adj, hT, el, er, out);
}

// Round 2
// 201.934 us; speedup vs baseline: 1.1436x; 1.1436x over previous
//
#include <hip/hip_runtime.h>
#include <hip/hip_bf16.h>

typedef __attribute__((ext_vector_type(8))) __bf16 bf16x8;
typedef __attribute__((ext_vector_type(4))) float f32x4;
typedef __attribute__((ext_vector_type(4))) int int4v;

#define NB 8
#define NN 2048
#define ND 256

// ---------------------------------------------------------------------------
// K0: wl[d] = sum_o a[o]*W[o][d], wr[d] = sum_o a[256+o]*W[o][d]
// ---------------------------------------------------------------------------
__global__ __launch_bounds__(256) void k0_wvec(
    const float* __restrict__ W, const float* __restrict__ a,
    float* __restrict__ wl, float* __restrict__ wr) {
  int w = threadIdx.x >> 6, l = threadIdx.x & 63;
  f32x4 sl = {0.f, 0.f, 0.f, 0.f}, sr = {0.f, 0.f, 0.f, 0.f};
  for (int oo = 0; oo < 64; ++oo) {
    int o = w * 64 + oo;
    f32x4 wv = *(const f32x4*)(W + o * ND + l * 4);
    float al = a[o], ar = a[ND + o];
    sl += al * wv;
    sr += ar * wv;
  }
  __shared__ f32x4 bl[4][64], br[4][64];
  bl[w][l] = sl;
  br[w][l] = sr;
  __syncthreads();
  if (w == 0) {
    f32x4 tl = bl[0][l] + bl[1][l] + bl[2][l] + bl[3][l];
    f32x4 tr = br[0][l] + br[1][l] + br[2][l] + br[3][l];
    *(f32x4*)(wl + l * 4) = tl;
    *(f32x4*)(wr + l * 4) = tr;
  }
}

// ---------------------------------------------------------------------------
// K2: el[bn] = x[bn,:]*wl (f32), er[bn] = x[bn,:]*wr. 64 rows/block, 4 thr/row.
// ---------------------------------------------------------------------------
__global__ __launch_bounds__(256) void k2_elr(
    const float* __restrict__ x, const float* __restrict__ wl,
    const float* __restrict__ wr, float* __restrict__ el,
    float* __restrict__ er) {
  int t = threadIdx.x;
  int r = t >> 2, q = t & 3;
  long row = (long)blockIdx.x * 64 + r;
  const f32x4* xr = (const f32x4*)(x + row * ND);
  const f32x4* wl4 = (const f32x4*)wl;
  const f32x4* wr4 = (const f32x4*)wr;
  float sl = 0.f, sr = 0.f;
#pragma unroll
  for (int ii = 0; ii < 16; ++ii) {
    int idx = q + (ii << 2);
    f32x4 xv = xr[idx];
    f32x4 lv = wl4[idx];
    f32x4 rv = wr4[idx];
    sl += xv[0] * lv[0] + xv[1] * lv[1] + xv[2] * lv[2] + xv[3] * lv[3];
    sr += xv[0] * rv[0] + xv[1] * rv[1] + xv[2] * rv[2] + xv[3] * rv[3];
  }
  sl += __shfl_xor(sl, 1);
  sl += __shfl_xor(sl, 2);
  sr += __shfl_xor(sr, 1);
  sr += __shfl_xor(sr, 2);
  if (q == 0) {
    el[row] = sl;
    er[row] = sr;
  }
}

// ---------------------------------------------------------------------------
// K1: h = x @ W^T via bf16 MFMA 16x16x32; write hT[b][d][n] bf16 (transposed
// through LDS, stride padded to 34 to kill bank conflicts on the read-out).
// ---------------------------------------------------------------------------
__global__ __launch_bounds__(256) void k1_h(
    const float* __restrict__ x, const float* __restrict__ W,
    __bf16* __restrict__ hT) {
  __shared__ __bf16 hlds[256 * 34];
  int tid = threadIdx.x;
  int wid = tid >> 6, lane = tid & 63;
  int msub = wid & 1, nh = wid >> 1;
  int lrow = lane & 15, kg = lane >> 4;
  int m0 = blockIdx.x * 32;
  int row = m0 + msub * 16 + lrow;

  f32x4 acc[8];
#pragma unroll
  for (int f = 0; f < 8; ++f) acc[f] = (f32x4){0.f, 0.f, 0.f, 0.f};

#pragma unroll
  for (int k0 = 0; k0 < ND; k0 += 32) {
    int kk = k0 + kg * 8;
    const f32x4* xa = (const f32x4*)(x + (long)row * ND + kk);
    f32x4 a0 = xa[0], a1 = xa[1];
    bf16x8 afrag;
    afrag[0] = (__bf16)a0[0]; afrag[1] = (__bf16)a0[1];
    afrag[2] = (__bf16)a0[2]; afrag[3] = (__bf16)a0[3];
    afrag[4] = (__bf16)a1[0]; afrag[5] = (__bf16)a1[1];
    afrag[6] = (__bf16)a1[2]; afrag[7] = (__bf16)a1[3];
#pragma unroll
    for (int f = 0; f < 8; ++f) {
      int o = nh * 128 + f * 16 + lrow;
      const f32x4* wb = (const f32x4*)(W + (long)o * ND + kk);
      f32x4 b0 = wb[0], b1 = wb[1];
      bf16x8 bfrag;
      bfrag[0] = (__bf16)b0[0]; bfrag[1] = (__bf16)b0[1];
      bfrag[2] = (__bf16)b0[2]; bfrag[3] = (__bf16)b0[3];
      bfrag[4] = (__bf16)b1[0]; bfrag[5] = (__bf16)b1[1];
      bfrag[6] = (__bf16)b1[2]; bfrag[7] = (__bf16)b1[3];
      acc[f] = __builtin_amdgcn_mfma_f32_16x16x32_bf16(afrag, bfrag, acc[f], 0, 0, 0);
    }
  }

#pragma unroll
  for (int f = 0; f < 8; ++f) {
    int d = nh * 128 + f * 16 + lrow;
#pragma unroll
    for (int r = 0; r < 4; ++r) {
      int nloc = msub * 16 + kg * 4 + r;
      hlds[d * 34 + nloc] = (__bf16)acc[f][r];
    }
  }
  __syncthreads();
  {
    int b = m0 >> 11;
    int n0 = m0 & (NN - 1);
    const int* src = (const int*)(hlds + tid * 34);
    int tmp[16];
#pragma unroll
    for (int j = 0; j < 16; ++j) tmp[j] = src[j];
    __bf16* dst = hT + ((long)b * ND + tid) * NN + n0;
#pragma unroll
    for (int j = 0; j < 4; ++j)
      *(int4v*)(dst + j * 8) = *(int4v*)(tmp + j * 4);
  }
}

// ---------------------------------------------------------------------------
// K3: fused mask + softmax + PV.  out[b,i,:] = (sum_j p_ij h_j) / (sum_j p_ij)
// p_ij = adj ? exp(lrelu(el_i+er_j) - (el_i+16)) : 0   (el_i+16 >= all scores)
//
// Round-2 changes:
//  - __launch_bounds__(256, 2): grid=512 -> 2 blocks/CU -> 2 waves/SIMD, so
//    allow ~256 VGPRs (was 44 -> compiler serialized the 8 B-frag loads).
//  - explicit 2-set register double-buffer (static indices via unroll 2):
//    iteration t+1's 12 loads are in flight during iteration t's MFMA+VALU.
//  - b = blockIdx&7: batch pinned to one XCD (round-robin dispatch) so the
//    1 MB hT slice of that batch stays resident in the XCD's 4 MB L2.
// ---------------------------------------------------------------------------
__global__ __launch_bounds__(256, 2) void k3_main(
    const int* __restrict__ adj, const __bf16* __restrict__ hT,
    const float* __restrict__ el, const float* __restrict__ er,
    float* __restrict__ out) {
  int blk = blockIdx.x;
  int b = blk & 7;    // batch -> XCD pin
  int it = blk >> 3;  // i-tile 0..63
  int wid = threadIdx.x >> 6, lane = threadIdx.x & 63;
  int isub = wid & 1, dh = wid >> 1;
  int lrow = lane & 15, kg = lane >> 4;
  int irow = it * 32 + isub * 16 + lrow;  // 0..2047 within batch

  float eli = el[b * NN + irow];
  float el16 = eli + 16.0f;
  const int* adjrow = adj + ((long)b * NN + irow) * NN;
  const float* erb = er + b * NN;
  int d_base = dh * 128 + lrow;
  int jb0 = kg * 8;  // this lane-group's 8-j slice within the 32-j step
  const __bf16* hptr = hT + (long)b * ND * NN + (long)d_base * NN + jb0;

  f32x4 acc[8];
#pragma unroll
  for (int f = 0; f < 8; ++f) acc[f] = (f32x4){0.f, 0.f, 0.f, 0.f};
  float den = 0.f;

  // two register sets for software pipeline
  bf16x8 bfr[2][8];
  int4v adv[2][2];
  f32x4 erv[2][2];

#define LOADT(s, t)                                                         \
  {                                                                         \
    int off = (t)*32;                                                       \
    _Pragma("unroll") for (int f = 0; f < 8; ++f)                           \
        bfr[s][f] = *(const bf16x8*)(hptr + (long)f * 16 * NN + off);       \
    adv[s][0] = *(const int4v*)(adjrow + off + jb0);                        \
    adv[s][1] = *(const int4v*)(adjrow + off + jb0 + 4);                    \
    erv[s][0] = *(const f32x4*)(erb + off + jb0);                           \
    erv[s][1] = *(const f32x4*)(erb + off + jb0 + 4);                       \
  }

  LOADT(0, 0);
#pragma unroll 2
  for (int t = 0; t < 64; ++t) {
    int cur = t & 1, nxt = cur ^ 1;
    if (t < 63) LOADT(nxt, t + 1);
    // p fragment (A-operand layout: row=l&15, k=(l>>4)*8+e contiguous)
    bf16x8 pfrag;
    float ps = 0.f;
#pragma unroll
    for (int e = 0; e < 8; ++e) {
      int aj = (e < 4) ? adv[cur][0][e] : adv[cur][1][e - 4];
      float erx = (e < 4) ? erv[cur][0][e] : erv[cur][1][e - 4];
      float z = eli + erx;
      float s = fmaxf(z, 0.2f * z);  // leaky relu
      float p = __expf(s - el16);
      p = (aj != 0) ? p : 0.0f;
      ps += p;
      pfrag[e] = (__bf16)p;
    }
    den += ps;
#pragma unroll
    for (int f = 0; f < 8; ++f)
      acc[f] = __builtin_amdgcn_mfma_f32_16x16x32_bf16(pfrag, bfr[cur][f], acc[f], 0, 0, 0);
  }
#undef LOADT

  // den: sum across the 4 k-groups (lanes with same l&15)
  den += __shfl_xor(den, 16);
  den += __shfl_xor(den, 32);
  float rdiv[4];
#pragma unroll
  for (int r = 0; r < 4; ++r) rdiv[r] = 1.0f / __shfl(den, kg * 4 + r);

  float* outb = out + ((long)b * NN + it * 32 + isub * 16) * ND;
#pragma unroll
  for (int f = 0; f < 8; ++f) {
    int dcol = d_base + f * 16;
#pragma unroll
    for (int r = 0; r < 4; ++r) {
      int rrow = kg * 4 + r;
      outb[(long)rrow * ND + dcol] = acc[f][r] * rdiv[r];
    }
  }
}

// ---------------------------------------------------------------------------
extern "C" void kernel_launch(void* const* d_in, const int* in_sizes, int n_in,
                              void* d_out, int out_size, void* d_ws,
                              size_t ws_size, hipStream_t stream) {
  const float* x = (const float*)d_in[0];
  const int* adj = (const int*)d_in[1];
  const float* W = (const float*)d_in[2];
  const float* a = (const float*)d_in[3];
  float* out = (float*)d_out;

  char* ws = (char*)d_ws;
  __bf16* hT = (__bf16*)ws;                                 // 8 MB
  float* el = (float*)(ws + 8u * 1024u * 1024u);            // 64 KB
  float* er = (float*)(ws + 8u * 1024u * 1024u + 65536u);   // 64 KB
  float* wl = (float*)(ws + 8u * 1024u * 1024u + 131072u);  // 1 KB
  float* wr = (float*)(ws + 8u * 1024u * 1024u + 132096u);  // 1 KB

  k0_wvec<<<dim3(1), dim3(256), 0, stream>>>(W, a, wl, wr);
  k2_elr<<<dim3(256), dim3(256), 0, stream>>>(x, wl, wr, el, er);
  k1_h<<<dim3(512), dim3(256), 0, stream>>>(x, W, hT);
  k3_main<<<dim3(512), dim3(256), 0, stream>>>(adj, hT, el, er, out);
}